// Round 10
// baseline (2519.581 us; speedup 1.0000x reference)
//
#include <hip/hip_runtime.h>
#include <hip/hip_fp16.h>

// GCN forward: 2x (MFMA fp16 GEMM + symmetric-normalized aggregation), fp32 in/out.
// CSR build: fixed-capacity dst-buckets, single scatter pass, per-bucket k_bnode.
// Aggregations: WIDE gathers (16 lanes x uint4 = 256B row, 4 edges/instr; 10 lanes
// x uint2 = 80B row, 6 edges/instr) + PERSISTENT WAVES with dynamic node stealing
// (atomic counter) to kill block-granularity degree imbalance.
//   out[i] = d_i * (sum_{s in N(i)} h_s[s] + h_s[i]) + b

#define F_IN  128
#define F_H   128
#define F_OUT 40

#define BK_SHIFT 7          // 128 nodes per bucket
#define BK_MAX   1024       // supports N <= 131072 (src < 2^25 for packing)
#define CHUNK    4096

typedef _Float16 half8v __attribute__((ext_vector_type(8)));
typedef float    f32x4  __attribute__((ext_vector_type(4)));

// ---- prep: W1/W2 -> fp16 swizzled images; zero bcnt + work counters ----

__global__ void k_prep(const float* __restrict__ W1, const float* __restrict__ W2,
                       __half* __restrict__ img1, __half* __restrict__ img2,
                       int* __restrict__ bcnt, int* __restrict__ ctr, int nbk) {
    int b = blockIdx.x;
    if (b < 64) {
        int idx = b * 256 + threadIdx.x;          // 128*128
        int j = idx >> 7, k = idx & 127;
        img1[j * 128 + (k ^ ((j & 7) << 3))] = __float2half_rn(W1[k * 128 + j]);
    } else if (b < 88) {
        int idx = (b - 64) * 256 + threadIdx.x;   // 48*128
        int j = idx >> 7, k = idx & 127;
        float v = (j < F_OUT) ? W2[k * F_OUT + j] : 0.f;
        img2[j * 128 + (k ^ ((j & 7) << 3))] = __float2half_rn(v);
    } else {
        for (int i = threadIdx.x; i < nbk; i += 256) bcnt[i] = 0;
        if (threadIdx.x < 2) ctr[threadIdx.x] = 0;
    }
}

// ---- scatter packed (src<<7 | dst&127) into fixed-cap bucket runs ----

__global__ __launch_bounds__(256) void k_bscatter(const int* __restrict__ src,
                                                  const int* __restrict__ dst,
                                                  int* __restrict__ bcnt,
                                                  int* __restrict__ ebuf,
                                                  int e, int nbk, int cap) {
    __shared__ int hist[BK_MAX];
    __shared__ int base[BK_MAX];
    __shared__ int run[BK_MAX];
    int e0 = blockIdx.x * CHUNK;
    int e1 = min(e0 + CHUNK, e);
    for (int i = threadIdx.x; i < nbk; i += 256) { hist[i] = 0; run[i] = 0; }
    __syncthreads();
    for (int i = e0 + threadIdx.x; i < e1; i += 256)
        atomicAdd(&hist[dst[i] >> BK_SHIFT], 1);
    __syncthreads();
    for (int i = threadIdx.x; i < nbk; i += 256) {
        int c = hist[i];
        base[i] = c ? (cap * i + atomicAdd(&bcnt[i], c)) : 0;
    }
    __syncthreads();
    for (int i = e0 + threadIdx.x; i < e1; i += 256) {
        int d = dst[i];
        int b = d >> BK_SHIFT;
        int r = atomicAdd(&run[b], 1);
        ebuf[base[b] + r] = (src[i] << BK_SHIFT) | (d & ((1 << BK_SHIFT) - 1));
    }
}

// ---- per-bucket: local hist -> (row_beg,deg)/dinv, local cursors -> col fill ----

__global__ __launch_bounds__(256) void k_bnode(const int* __restrict__ ebuf,
                                               const int* __restrict__ bcnt,
                                               int2* __restrict__ rbd,
                                               float* __restrict__ dinv,
                                               int* __restrict__ col,
                                               int n, int cap) {
    __shared__ int hist[128];
    __shared__ int sc[128];
    __shared__ int cur[128];
    const int b   = blockIdx.x;
    const int tid = threadIdx.x;
    const int e0 = b * cap;
    const int e1 = e0 + bcnt[b];

    if (tid < 128) hist[tid] = 0;
    __syncthreads();
    for (int i = e0 + tid; i < e1; i += 256)
        atomicAdd(&hist[ebuf[i] & 127], 1);
    __syncthreads();
    if (tid < 128) sc[tid] = hist[tid];
    __syncthreads();
    for (int off = 1; off < 128; off <<= 1) {
        int t = 0;
        if (tid < 128 && tid >= off) t = sc[tid - off];
        __syncthreads();
        if (tid < 128) sc[tid] += t;
        __syncthreads();
    }
    if (tid < 128) {
        int node = (b << BK_SHIFT) + tid;
        int excl = sc[tid] - hist[tid];
        if (node < n) {
            rbd[node] = make_int2(e0 + excl, hist[tid]);
            dinv[node] = rsqrtf((float)hist[tid] + 1.0f);   // +1 self-loop
        }
        cur[tid] = e0 + excl;
    }
    __syncthreads();
    for (int i = e0 + tid; i < e1; i += 256) {
        int w = ebuf[i];
        int pos = atomicAdd(&cur[w & 127], 1);
        col[pos] = w >> BK_SHIFT;
    }
}

// ---- GEMM 1 (MFMA): h1s = fp16( dinv .* (x @ W1) ) ----

__global__ __launch_bounds__(256) void k_gemm1(const float* __restrict__ x,
                                               const __half* __restrict__ Wimg,
                                               const float* __restrict__ dinv,
                                               __half* __restrict__ h, int n) {
    __shared__ __half wlds[128 * 128];
    const int tid = threadIdx.x;
#pragma unroll
    for (int it = 0; it < 8; ++it) {
        int i = tid * 8 + it * 2048;
        *(uint4*)&wlds[i] = *(const uint4*)&Wimg[i];
    }

    const int l  = tid & 63;
    const int g  = l >> 4;
    const int r0 = blockIdx.x * 64 + (tid >> 6) * 16;
    int row = r0 + (l & 15);
    if (row > n - 1) row = n - 1;

    const float* xb = x + row * F_IN + g * 8;
    half8v afr[4];
#pragma unroll
    for (int kk = 0; kk < 4; ++kk) {
        float4 u0 = *(const float4*)(xb + kk * 32);
        float4 u1 = *(const float4*)(xb + kk * 32 + 4);
        half8v a;
        a[0] = (_Float16)u0.x; a[1] = (_Float16)u0.y;
        a[2] = (_Float16)u0.z; a[3] = (_Float16)u0.w;
        a[4] = (_Float16)u1.x; a[5] = (_Float16)u1.y;
        a[6] = (_Float16)u1.z; a[7] = (_Float16)u1.w;
        afr[kk] = a;
    }
    __syncthreads();

    const char* wb = (const char*)wlds;
    const int swz = (l & 7) << 4;
    f32x4 acc[8] = {};
#pragma unroll
    for (int ct = 0; ct < 8; ++ct) {
        const int base = (ct * 16 + (l & 15)) * 256;
#pragma unroll
        for (int kk = 0; kk < 4; ++kk) {
            half8v bfr = *(const half8v*)(wb + base + ((kk * 64 + g * 16) ^ swz));
            acc[ct] = __builtin_amdgcn_mfma_f32_16x16x32_f16(afr[kk], bfr, acc[ct], 0, 0, 0);
        }
    }

    const int orow0 = r0 + g * 4;
    float dv[4];
#pragma unroll
    for (int b = 0; b < 4; ++b) {
        int r = orow0 + b;
        dv[b] = (r < n) ? dinv[r] : 0.f;
    }
#pragma unroll
    for (int ct = 0; ct < 8; ++ct) {
#pragma unroll
        for (int b = 0; b < 4; ++b) {
            int r = orow0 + b;
            if (r < n)
                h[r * F_H + ct * 16 + (l & 15)] = __float2half_rn(acc[ct][b] * dv[b]);
        }
    }
}

// ---- Aggregation layer 1: persistent waves, 16 lanes x uint4, 4 edges/instr ----

#define UNPK8(A, u) { \
    float2 t0 = __half22float2(*(__half2*)&(u).x); \
    float2 t1 = __half22float2(*(__half2*)&(u).y); \
    float2 t2 = __half22float2(*(__half2*)&(u).z); \
    float2 t3 = __half22float2(*(__half2*)&(u).w); \
    A[0] += t0.x; A[1] += t0.y; A[2] += t1.x; A[3] += t1.y; \
    A[4] += t2.x; A[5] += t2.y; A[6] += t3.x; A[7] += t3.y; }

__global__ __launch_bounds__(256) void k_agg1r(const __half* __restrict__ h1s,
                                               const int2* __restrict__ rbd,
                                               const int* __restrict__ col,
                                               const float* __restrict__ dinv,
                                               const float* __restrict__ b1,
                                               __half* __restrict__ out1,
                                               int* __restrict__ ctr, int n) {
    const int lane = threadIdx.x & 63;
    const int q = lane >> 4;         // edge slot 0..3
    const int f = lane & 15;         // owns halfs 8f..8f+7 of the row
    const uint4* hb = (const uint4*)h1s + f;   // row = 16 uint4

    for (;;) {
        int t0 = 0;
        if (lane == 0) t0 = atomicAdd(ctr, 1);
        int wid = __shfl(t0, 0);
        if (wid >= n) return;

        int2 bd = rbd[wid];
        int beg = bd.x, end = bd.x + bd.y;

        float ax[8] = {}, bx[8] = {};
        int idx = beg;
        for (; idx + 8 <= end; idx += 8) {          // 8 edges: two quad-gathers
            int s0 = col[idx + q];
            int s1 = col[idx + 4 + q];
            uint4 u0 = hb[s0 << 4];
            uint4 u1 = hb[s1 << 4];
            UNPK8(ax, u0);
            UNPK8(bx, u1);
        }
        if (idx + 4 <= end) {                       // one quad
            int s = col[idx + q];
            uint4 u = hb[s << 4];
            UNPK8(ax, u);
            idx += 4;
        }
        int rem = end - idx;                        // 0..3
        if (q < rem) {
            int s = col[idx + q];
            uint4 u = hb[s << 4];
            UNPK8(bx, u);
        }
#pragma unroll
        for (int j = 0; j < 8; ++j) ax[j] += bx[j];
#pragma unroll
        for (int j = 0; j < 8; ++j) {
            ax[j] += __shfl(ax[j], lane ^ 16);
            ax[j] += __shfl(ax[j], lane ^ 32);
        }
        if (q == 0) {                               // lanes 0..15 finalize
            uint4 hu = hb[wid << 4];                // self (already dinv-scaled)
            float hv[8] = {};
            UNPK8(hv, hu);
            float di = dinv[wid];
            float4 bv0 = *(const float4*)&b1[8 * f];
            float4 bv1 = *(const float4*)&b1[8 * f + 4];
            float o[8];
            o[0] = fmaxf(fmaf(ax[0] + hv[0], di, bv0.x), 0.f);
            o[1] = fmaxf(fmaf(ax[1] + hv[1], di, bv0.y), 0.f);
            o[2] = fmaxf(fmaf(ax[2] + hv[2], di, bv0.z), 0.f);
            o[3] = fmaxf(fmaf(ax[3] + hv[3], di, bv0.w), 0.f);
            o[4] = fmaxf(fmaf(ax[4] + hv[4], di, bv1.x), 0.f);
            o[5] = fmaxf(fmaf(ax[5] + hv[5], di, bv1.y), 0.f);
            o[6] = fmaxf(fmaf(ax[6] + hv[6], di, bv1.z), 0.f);
            o[7] = fmaxf(fmaf(ax[7] + hv[7], di, bv1.w), 0.f);
            __half2 p0 = __floats2half2_rn(o[0], o[1]);
            __half2 p1 = __floats2half2_rn(o[2], o[3]);
            __half2 p2 = __floats2half2_rn(o[4], o[5]);
            __half2 p3 = __floats2half2_rn(o[6], o[7]);
            uint4 pk;
            pk.x = *(unsigned int*)&p0; pk.y = *(unsigned int*)&p1;
            pk.z = *(unsigned int*)&p2; pk.w = *(unsigned int*)&p3;
            *(uint4*)&out1[(wid << 7) + 8 * f] = pk;
        }
    }
}

// ---- GEMM 2 (MFMA): h2s = fp16( dinv .* (out1 @ W2) ) ----

__global__ __launch_bounds__(256) void k_gemm2(const __half* __restrict__ xin,
                                               const __half* __restrict__ Wimg,
                                               const float* __restrict__ dinv,
                                               __half* __restrict__ h, int n) {
    __shared__ __half wlds[48 * 128];
    const int tid = threadIdx.x;
#pragma unroll
    for (int it = 0; it < 3; ++it) {
        int i = tid * 8 + it * 2048;
        *(uint4*)&wlds[i] = *(const uint4*)&Wimg[i];
    }

    const int l  = tid & 63;
    const int g  = l >> 4;
    const int r0 = blockIdx.x * 64 + (tid >> 6) * 16;
    int row = r0 + (l & 15);
    if (row > n - 1) row = n - 1;

    const __half* ab = xin + row * F_H + g * 8;
    half8v afr[4];
#pragma unroll
    for (int kk = 0; kk < 4; ++kk) afr[kk] = *(const half8v*)(ab + kk * 32);
    __syncthreads();

    const char* wb = (const char*)wlds;
    const int swz = (l & 7) << 4;
    f32x4 acc[3] = {};
#pragma unroll
    for (int ct = 0; ct < 3; ++ct) {
        const int base = (ct * 16 + (l & 15)) * 256;
#pragma unroll
        for (int kk = 0; kk < 4; ++kk) {
            half8v bfr = *(const half8v*)(wb + base + ((kk * 64 + g * 16) ^ swz));
            acc[ct] = __builtin_amdgcn_mfma_f32_16x16x32_f16(afr[kk], bfr, acc[ct], 0, 0, 0);
        }
    }

    const int orow0 = r0 + g * 4;
    float dv[4];
#pragma unroll
    for (int b = 0; b < 4; ++b) {
        int r = orow0 + b;
        dv[b] = (r < n) ? dinv[r] : 0.f;
    }
#pragma unroll
    for (int ct = 0; ct < 3; ++ct) {
        int c = ct * 16 + (l & 15);
#pragma unroll
        for (int b = 0; b < 4; ++b) {
            int r = orow0 + b;
            if (r < n && c < F_OUT)
                h[r * F_OUT + c] = __float2half_rn(acc[ct][b] * dv[b]);
        }
    }
}

// ---- Aggregation layer 2: persistent waves, 10 lanes x uint2, 6 edges/instr ----

#define UNPK4(A, u) { \
    float2 t0 = __half22float2(*(__half2*)&(u).x); \
    float2 t1 = __half22float2(*(__half2*)&(u).y); \
    A[0] += t0.x; A[1] += t0.y; A[2] += t1.x; A[3] += t1.y; }

__global__ __launch_bounds__(256) void k_agg2(const __half* __restrict__ h2s,
                                              const int2* __restrict__ rbd,
                                              const int* __restrict__ col,
                                              const float* __restrict__ dinv,
                                              const float* __restrict__ b2,
                                              float* __restrict__ out,
                                              int* __restrict__ ctr, int n) {
    const int lane = threadIdx.x & 63;
    const int g = lane / 10;               // edge slot 0..5 (6 for lanes 60-63)
    const int f = lane - g * 10;           // owns halfs 4f..4f+3
    const bool act = (g < 6);
    const uint2* hb = (const uint2*)h2s + f;   // row = 10 uint2 (80 B)

    for (;;) {
        int t0 = 0;
        if (lane == 0) t0 = atomicAdd(ctr, 1);
        int wid = __shfl(t0, 0);
        if (wid >= n) return;

        int2 bd = rbd[wid];
        int beg = bd.x, end = bd.x + bd.y;

        float ax[4] = {}, bx[4] = {};
        int idx = beg;
        if (act) {
            for (; idx + 12 <= end; idx += 12) {     // 12 edges: two hex-gathers
                int s0 = col[idx + g];
                int s1 = col[idx + 6 + g];
                uint2 u0 = hb[s0 * 10];
                uint2 u1 = hb[s1 * 10];
                UNPK4(ax, u0);
                UNPK4(bx, u1);
            }
            if (idx + 6 <= end) {
                int s = col[idx + g];
                uint2 u = hb[s * 10];
                UNPK4(ax, u);
                idx += 6;
            }
            int rem = end - idx;                     // 0..5
            if (g < rem) {
                int s = col[idx + g];
                uint2 u = hb[s * 10];
                UNPK4(bx, u);
            }
        }
#pragma unroll
        for (int j = 0; j < 4; ++j) ax[j] += bx[j];
        // 6-group combine: +30, then +10 and +20
#pragma unroll
        for (int j = 0; j < 4; ++j) {
            float t = ax[j] + __shfl(ax[j], lane + 30);
            ax[j] = t + __shfl(t, lane + 10) + __shfl(t, lane + 20);
        }
        if (g == 0) {                                // lanes 0..9 finalize
            uint2 hu = hb[wid * 10];
            float hv[4] = {};
            UNPK4(hv, hu);
            float di = dinv[wid];
            float4 bv = *(const float4*)&b2[4 * f];
            float4 o;
            o.x = fmaf(ax[0] + hv[0], di, bv.x);
            o.y = fmaf(ax[1] + hv[1], di, bv.y);
            o.z = fmaf(ax[2] + hv[2], di, bv.z);
            o.w = fmaf(ax[3] + hv[3], di, bv.w);
            *(float4*)&out[wid * F_OUT + 4 * f] = o;
        }
    }
}

// ---------------- launch ----------------

extern "C" void kernel_launch(void* const* d_in, const int* in_sizes, int n_in,
                              void* d_out, int out_size, void* d_ws, size_t ws_size,
                              hipStream_t stream) {
    const float* x  = (const float*)d_in[0];
    const int*   ei = (const int*)d_in[1];
    const float* W1 = (const float*)d_in[2];
    const float* b1 = (const float*)d_in[3];
    const float* W2 = (const float*)d_in[4];
    const float* b2 = (const float*)d_in[5];
    float* out = (float*)d_out;

    const int N = in_sizes[0] / F_IN;     // 100000
    const int E = in_sizes[1] / 2;        // 1600000
    const int* src = ei;
    const int* dst = ei + E;
    const int nbk = (N + (1 << BK_SHIFT) - 1) >> BK_SHIFT;   // 782
    const int cap = (((2 * E) / nbk) + 63) & ~63;            // ~4096

    char* ws = (char*)d_ws;
    size_t off = 0;
    auto alloc = [&](size_t bytes) -> void* {
        off = (off + 255) & ~(size_t)255;
        void* p = ws + off;
        off += bytes;
        return p;
    };
    float*  dinv    = (float*) alloc((size_t)N * 4);
    int2*   rbd     = (int2*)  alloc((size_t)N * 8);
    int*    bcnt    = (int*)   alloc(BK_MAX * 4);
    int*    ctr     = (int*)   alloc(2 * 4);
    __half* W1img   = (__half*)alloc(128 * 128 * 2);
    __half* W2img   = (__half*)alloc(48 * 128 * 2);
    int*    ebuf    = (int*)   alloc((size_t)nbk * cap * 4);
    int*    col     = (int*)   alloc((size_t)nbk * cap * 4);
    __half* h1s     = (__half*)alloc((size_t)N * F_H * 2);
    __half* out1h   = (__half*)alloc((size_t)N * F_H * 2);
    __half* h2s     = h1s;     // h1s dead after agg1 -> reuse

    const int gC = (E + CHUNK - 1) / CHUNK;   // 391
    const int gP = 1792;                      // persistent blocks (7/CU)

    k_prep    <<<89, 256, 0, stream>>>(W1, W2, W1img, W2img, bcnt, ctr, nbk);
    k_bscatter<<<gC, 256, 0, stream>>>(src, dst, bcnt, ebuf, E, nbk, cap);
    k_bnode   <<<nbk, 256, 0, stream>>>(ebuf, bcnt, rbd, dinv, col, N, cap);

    k_gemm1<<<(N + 63) / 64, 256, 0, stream>>>(x, W1img, dinv, h1s, N);
    k_agg1r<<<gP, 256, 0, stream>>>(h1s, rbd, col, dinv, b1, out1h, ctr, N);
    k_gemm2<<<(N + 63) / 64, 256, 0, stream>>>(out1h, W2img, dinv, h2s, N);
    k_agg2 <<<gP, 256, 0, stream>>>(h2s, rbd, col, dinv, b2, out, ctr + 1, N);
}

// Round 11
// 185.190 us; speedup vs baseline: 13.6054x; 13.6054x over previous
//
#include <hip/hip_runtime.h>
#include <hip/hip_fp16.h>

// GCN forward: 2x (MFMA fp16 GEMM + symmetric-normalized aggregation), fp32 in/out.
// CSR build: fixed-capacity dst-buckets, single scatter pass, per-bucket k_bnode.
// Aggregations: WIDE gathers (16 lanes x uint4 = 256B row, 4 edges/instr; 10 lanes
// x uint2 = 80B row, 6 edges/instr), static per-wave node assignment (R9 form —
// dynamic atomic stealing regressed 13x due to single-line RMW serialization).
//   out[i] = d_i * (sum_{s in N(i)} h_s[s] + h_s[i]) + b

#define F_IN  128
#define F_H   128
#define F_OUT 40

#define BK_SHIFT 7          // 128 nodes per bucket
#define BK_MAX   1024       // supports N <= 131072 (src < 2^25 for packing)
#define CHUNK    4096

typedef _Float16 half8v __attribute__((ext_vector_type(8)));
typedef float    f32x4  __attribute__((ext_vector_type(4)));

// ---- prep: W1/W2 -> fp16 swizzled images; zero bcnt ----

__global__ void k_prep(const float* __restrict__ W1, const float* __restrict__ W2,
                       __half* __restrict__ img1, __half* __restrict__ img2,
                       int* __restrict__ bcnt, int nbk) {
    int b = blockIdx.x;
    if (b < 64) {
        int idx = b * 256 + threadIdx.x;          // 128*128
        int j = idx >> 7, k = idx & 127;
        img1[j * 128 + (k ^ ((j & 7) << 3))] = __float2half_rn(W1[k * 128 + j]);
    } else if (b < 88) {
        int idx = (b - 64) * 256 + threadIdx.x;   // 48*128
        int j = idx >> 7, k = idx & 127;
        float v = (j < F_OUT) ? W2[k * F_OUT + j] : 0.f;
        img2[j * 128 + (k ^ ((j & 7) << 3))] = __float2half_rn(v);
    } else {
        for (int i = threadIdx.x; i < nbk; i += 256) bcnt[i] = 0;
    }
}

// ---- scatter packed (src<<7 | dst&127) into fixed-cap bucket runs ----

__global__ __launch_bounds__(256) void k_bscatter(const int* __restrict__ src,
                                                  const int* __restrict__ dst,
                                                  int* __restrict__ bcnt,
                                                  int* __restrict__ ebuf,
                                                  int e, int nbk, int cap) {
    __shared__ int hist[BK_MAX];
    __shared__ int base[BK_MAX];
    __shared__ int run[BK_MAX];
    int e0 = blockIdx.x * CHUNK;
    int e1 = min(e0 + CHUNK, e);
    for (int i = threadIdx.x; i < nbk; i += 256) { hist[i] = 0; run[i] = 0; }
    __syncthreads();
    for (int i = e0 + threadIdx.x; i < e1; i += 256)
        atomicAdd(&hist[dst[i] >> BK_SHIFT], 1);
    __syncthreads();
    for (int i = threadIdx.x; i < nbk; i += 256) {
        int c = hist[i];
        base[i] = c ? (cap * i + atomicAdd(&bcnt[i], c)) : 0;
    }
    __syncthreads();
    for (int i = e0 + threadIdx.x; i < e1; i += 256) {
        int d = dst[i];
        int b = d >> BK_SHIFT;
        int r = atomicAdd(&run[b], 1);
        ebuf[base[b] + r] = (src[i] << BK_SHIFT) | (d & ((1 << BK_SHIFT) - 1));
    }
}

// ---- per-bucket: local hist -> (row_beg,deg)/dinv, local cursors -> col fill ----

__global__ __launch_bounds__(256) void k_bnode(const int* __restrict__ ebuf,
                                               const int* __restrict__ bcnt,
                                               int2* __restrict__ rbd,
                                               float* __restrict__ dinv,
                                               int* __restrict__ col,
                                               int n, int cap) {
    __shared__ int hist[128];
    __shared__ int sc[128];
    __shared__ int cur[128];
    const int b   = blockIdx.x;
    const int tid = threadIdx.x;
    const int e0 = b * cap;
    const int e1 = e0 + bcnt[b];

    if (tid < 128) hist[tid] = 0;
    __syncthreads();
    for (int i = e0 + tid; i < e1; i += 256)
        atomicAdd(&hist[ebuf[i] & 127], 1);
    __syncthreads();
    if (tid < 128) sc[tid] = hist[tid];
    __syncthreads();
    for (int off = 1; off < 128; off <<= 1) {
        int t = 0;
        if (tid < 128 && tid >= off) t = sc[tid - off];
        __syncthreads();
        if (tid < 128) sc[tid] += t;
        __syncthreads();
    }
    if (tid < 128) {
        int node = (b << BK_SHIFT) + tid;
        int excl = sc[tid] - hist[tid];
        if (node < n) {
            rbd[node] = make_int2(e0 + excl, hist[tid]);
            dinv[node] = rsqrtf((float)hist[tid] + 1.0f);   // +1 self-loop
        }
        cur[tid] = e0 + excl;
    }
    __syncthreads();
    for (int i = e0 + tid; i < e1; i += 256) {
        int w = ebuf[i];
        int pos = atomicAdd(&cur[w & 127], 1);
        col[pos] = w >> BK_SHIFT;
    }
}

// ---- GEMM 1 (MFMA): h1s = fp16( dinv .* (x @ W1) ) ----

__global__ __launch_bounds__(256) void k_gemm1(const float* __restrict__ x,
                                               const __half* __restrict__ Wimg,
                                               const float* __restrict__ dinv,
                                               __half* __restrict__ h, int n) {
    __shared__ __half wlds[128 * 128];
    const int tid = threadIdx.x;
#pragma unroll
    for (int it = 0; it < 8; ++it) {
        int i = tid * 8 + it * 2048;
        *(uint4*)&wlds[i] = *(const uint4*)&Wimg[i];
    }

    const int l  = tid & 63;
    const int g  = l >> 4;
    const int r0 = blockIdx.x * 64 + (tid >> 6) * 16;
    int row = r0 + (l & 15);
    if (row > n - 1) row = n - 1;

    const float* xb = x + row * F_IN + g * 8;
    half8v afr[4];
#pragma unroll
    for (int kk = 0; kk < 4; ++kk) {
        float4 u0 = *(const float4*)(xb + kk * 32);
        float4 u1 = *(const float4*)(xb + kk * 32 + 4);
        half8v a;
        a[0] = (_Float16)u0.x; a[1] = (_Float16)u0.y;
        a[2] = (_Float16)u0.z; a[3] = (_Float16)u0.w;
        a[4] = (_Float16)u1.x; a[5] = (_Float16)u1.y;
        a[6] = (_Float16)u1.z; a[7] = (_Float16)u1.w;
        afr[kk] = a;
    }
    __syncthreads();

    const char* wb = (const char*)wlds;
    const int swz = (l & 7) << 4;
    f32x4 acc[8] = {};
#pragma unroll
    for (int ct = 0; ct < 8; ++ct) {
        const int base = (ct * 16 + (l & 15)) * 256;
#pragma unroll
        for (int kk = 0; kk < 4; ++kk) {
            half8v bfr = *(const half8v*)(wb + base + ((kk * 64 + g * 16) ^ swz));
            acc[ct] = __builtin_amdgcn_mfma_f32_16x16x32_f16(afr[kk], bfr, acc[ct], 0, 0, 0);
        }
    }

    const int orow0 = r0 + g * 4;
    float dv[4];
#pragma unroll
    for (int b = 0; b < 4; ++b) {
        int r = orow0 + b;
        dv[b] = (r < n) ? dinv[r] : 0.f;
    }
#pragma unroll
    for (int ct = 0; ct < 8; ++ct) {
#pragma unroll
        for (int b = 0; b < 4; ++b) {
            int r = orow0 + b;
            if (r < n)
                h[r * F_H + ct * 16 + (l & 15)] = __float2half_rn(acc[ct][b] * dv[b]);
        }
    }
}

// ---- Aggregation layer 1: 16 lanes x uint4 per 256B row, 4 edges/instr ----

#define UNPK8(A, u) { \
    float2 t0 = __half22float2(*(__half2*)&(u).x); \
    float2 t1 = __half22float2(*(__half2*)&(u).y); \
    float2 t2 = __half22float2(*(__half2*)&(u).z); \
    float2 t3 = __half22float2(*(__half2*)&(u).w); \
    A[0] += t0.x; A[1] += t0.y; A[2] += t1.x; A[3] += t1.y; \
    A[4] += t2.x; A[5] += t2.y; A[6] += t3.x; A[7] += t3.y; }

__global__ __launch_bounds__(256) void k_agg1r(const __half* __restrict__ h1s,
                                               const int2* __restrict__ rbd,
                                               const int* __restrict__ col,
                                               const float* __restrict__ dinv,
                                               const float* __restrict__ b1,
                                               __half* __restrict__ out1, int n) {
    int wid = (blockIdx.x * 256 + threadIdx.x) >> 6;
    int lane = threadIdx.x & 63;
    if (wid >= n) return;
    int2 bd = rbd[wid];
    int beg = bd.x, end = bd.x + bd.y;
    const int q = lane >> 4;         // edge slot 0..3
    const int f = lane & 15;         // owns halfs 8f..8f+7 of the row
    const uint4* hb = (const uint4*)h1s + f;   // row = 16 uint4

    float ax[8] = {}, bx[8] = {};
    int idx = beg;
    for (; idx + 8 <= end; idx += 8) {          // 8 edges: two quad-gathers
        int s0 = col[idx + q];
        int s1 = col[idx + 4 + q];
        uint4 u0 = hb[s0 << 4];
        uint4 u1 = hb[s1 << 4];
        UNPK8(ax, u0);
        UNPK8(bx, u1);
    }
    if (idx + 4 <= end) {                       // one quad
        int s = col[idx + q];
        uint4 u = hb[s << 4];
        UNPK8(ax, u);
        idx += 4;
    }
    int rem = end - idx;                        // 0..3
    if (q < rem) {
        int s = col[idx + q];
        uint4 u = hb[s << 4];
        UNPK8(bx, u);
    }
#pragma unroll
    for (int j = 0; j < 8; ++j) ax[j] += bx[j];
#pragma unroll
    for (int j = 0; j < 8; ++j) {
        ax[j] += __shfl(ax[j], lane ^ 16);
        ax[j] += __shfl(ax[j], lane ^ 32);
    }
    if (q == 0) {                               // lanes 0..15 finalize
        uint4 hu = hb[wid << 4];                // self (already dinv-scaled)
        float hv[8] = {};
        UNPK8(hv, hu);
        float di = dinv[wid];
        float4 bv0 = *(const float4*)&b1[8 * f];
        float4 bv1 = *(const float4*)&b1[8 * f + 4];
        float o[8];
        o[0] = fmaxf(fmaf(ax[0] + hv[0], di, bv0.x), 0.f);
        o[1] = fmaxf(fmaf(ax[1] + hv[1], di, bv0.y), 0.f);
        o[2] = fmaxf(fmaf(ax[2] + hv[2], di, bv0.z), 0.f);
        o[3] = fmaxf(fmaf(ax[3] + hv[3], di, bv0.w), 0.f);
        o[4] = fmaxf(fmaf(ax[4] + hv[4], di, bv1.x), 0.f);
        o[5] = fmaxf(fmaf(ax[5] + hv[5], di, bv1.y), 0.f);
        o[6] = fmaxf(fmaf(ax[6] + hv[6], di, bv1.z), 0.f);
        o[7] = fmaxf(fmaf(ax[7] + hv[7], di, bv1.w), 0.f);
        __half2 p0 = __floats2half2_rn(o[0], o[1]);
        __half2 p1 = __floats2half2_rn(o[2], o[3]);
        __half2 p2 = __floats2half2_rn(o[4], o[5]);
        __half2 p3 = __floats2half2_rn(o[6], o[7]);
        uint4 pk;
        pk.x = *(unsigned int*)&p0; pk.y = *(unsigned int*)&p1;
        pk.z = *(unsigned int*)&p2; pk.w = *(unsigned int*)&p3;
        *(uint4*)&out1[(wid << 7) + 8 * f] = pk;
    }
}

// ---- GEMM 2 (MFMA): h2s = fp16( dinv .* (out1 @ W2) ) ----

__global__ __launch_bounds__(256) void k_gemm2(const __half* __restrict__ xin,
                                               const __half* __restrict__ Wimg,
                                               const float* __restrict__ dinv,
                                               __half* __restrict__ h, int n) {
    __shared__ __half wlds[48 * 128];
    const int tid = threadIdx.x;
#pragma unroll
    for (int it = 0; it < 3; ++it) {
        int i = tid * 8 + it * 2048;
        *(uint4*)&wlds[i] = *(const uint4*)&Wimg[i];
    }

    const int l  = tid & 63;
    const int g  = l >> 4;
    const int r0 = blockIdx.x * 64 + (tid >> 6) * 16;
    int row = r0 + (l & 15);
    if (row > n - 1) row = n - 1;

    const __half* ab = xin + row * F_H + g * 8;
    half8v afr[4];
#pragma unroll
    for (int kk = 0; kk < 4; ++kk) afr[kk] = *(const half8v*)(ab + kk * 32);
    __syncthreads();

    const char* wb = (const char*)wlds;
    const int swz = (l & 7) << 4;
    f32x4 acc[3] = {};
#pragma unroll
    for (int ct = 0; ct < 3; ++ct) {
        const int base = (ct * 16 + (l & 15)) * 256;
#pragma unroll
        for (int kk = 0; kk < 4; ++kk) {
            half8v bfr = *(const half8v*)(wb + base + ((kk * 64 + g * 16) ^ swz));
            acc[ct] = __builtin_amdgcn_mfma_f32_16x16x32_f16(afr[kk], bfr, acc[ct], 0, 0, 0);
        }
    }

    const int orow0 = r0 + g * 4;
    float dv[4];
#pragma unroll
    for (int b = 0; b < 4; ++b) {
        int r = orow0 + b;
        dv[b] = (r < n) ? dinv[r] : 0.f;
    }
#pragma unroll
    for (int ct = 0; ct < 3; ++ct) {
        int c = ct * 16 + (l & 15);
#pragma unroll
        for (int b = 0; b < 4; ++b) {
            int r = orow0 + b;
            if (r < n && c < F_OUT)
                h[r * F_OUT + c] = __float2half_rn(acc[ct][b] * dv[b]);
        }
    }
}

// ---- Aggregation layer 2: 10 lanes x uint2 per 80B row, 6 edges/instr ----

#define UNPK4(A, u) { \
    float2 t0 = __half22float2(*(__half2*)&(u).x); \
    float2 t1 = __half22float2(*(__half2*)&(u).y); \
    A[0] += t0.x; A[1] += t0.y; A[2] += t1.x; A[3] += t1.y; }

__global__ __launch_bounds__(256) void k_agg2(const __half* __restrict__ h2s,
                                              const int2* __restrict__ rbd,
                                              const int* __restrict__ col,
                                              const float* __restrict__ dinv,
                                              const float* __restrict__ b2,
                                              float* __restrict__ out, int n) {
    int wid = (blockIdx.x * 256 + threadIdx.x) >> 6;
    int lane = threadIdx.x & 63;
    if (wid >= n) return;
    int g = lane / 10;               // edge slot 0..5 (6 for lanes 60-63)
    int f = lane - g * 10;           // owns halfs 4f..4f+3
    bool act = (g < 6);
    const uint2* hb = (const uint2*)h2s + f;   // row = 10 uint2 (80 B)
    int2 bd = rbd[wid];
    int beg = bd.x, end = bd.x + bd.y;

    float ax[4] = {}, bx[4] = {};
    int idx = beg;
    if (act) {
        for (; idx + 12 <= end; idx += 12) {     // 12 edges: two hex-gathers
            int s0 = col[idx + g];
            int s1 = col[idx + 6 + g];
            uint2 u0 = hb[s0 * 10];
            uint2 u1 = hb[s1 * 10];
            UNPK4(ax, u0);
            UNPK4(bx, u1);
        }
        if (idx + 6 <= end) {
            int s = col[idx + g];
            uint2 u = hb[s * 10];
            UNPK4(ax, u);
            idx += 6;
        }
        int rem = end - idx;                     // 0..5
        if (g < rem) {
            int s = col[idx + g];
            uint2 u = hb[s * 10];
            UNPK4(bx, u);
        }
    }
#pragma unroll
    for (int j = 0; j < 4; ++j) ax[j] += bx[j];
    // 6-group combine: +30, then +10 and +20
#pragma unroll
    for (int j = 0; j < 4; ++j) {
        float t = ax[j] + __shfl(ax[j], lane + 30);
        ax[j] = t + __shfl(t, lane + 10) + __shfl(t, lane + 20);
    }
    if (g == 0) {                                // lanes 0..9 finalize
        uint2 hu = hb[wid * 10];
        float hv[4] = {};
        UNPK4(hv, hu);
        float di = dinv[wid];
        float4 bv = *(const float4*)&b2[4 * f];
        float4 o;
        o.x = fmaf(ax[0] + hv[0], di, bv.x);
        o.y = fmaf(ax[1] + hv[1], di, bv.y);
        o.z = fmaf(ax[2] + hv[2], di, bv.z);
        o.w = fmaf(ax[3] + hv[3], di, bv.w);
        *(float4*)&out[wid * F_OUT + 4 * f] = o;
    }
}

// ---------------- launch ----------------

extern "C" void kernel_launch(void* const* d_in, const int* in_sizes, int n_in,
                              void* d_out, int out_size, void* d_ws, size_t ws_size,
                              hipStream_t stream) {
    const float* x  = (const float*)d_in[0];
    const int*   ei = (const int*)d_in[1];
    const float* W1 = (const float*)d_in[2];
    const float* b1 = (const float*)d_in[3];
    const float* W2 = (const float*)d_in[4];
    const float* b2 = (const float*)d_in[5];
    float* out = (float*)d_out;

    const int N = in_sizes[0] / F_IN;     // 100000
    const int E = in_sizes[1] / 2;        // 1600000
    const int* src = ei;
    const int* dst = ei + E;
    const int nbk = (N + (1 << BK_SHIFT) - 1) >> BK_SHIFT;   // 782
    const int cap = (((2 * E) / nbk) + 63) & ~63;            // ~4096

    char* ws = (char*)d_ws;
    size_t off = 0;
    auto alloc = [&](size_t bytes) -> void* {
        off = (off + 255) & ~(size_t)255;
        void* p = ws + off;
        off += bytes;
        return p;
    };
    float*  dinv    = (float*) alloc((size_t)N * 4);
    int2*   rbd     = (int2*)  alloc((size_t)N * 8);
    int*    bcnt    = (int*)   alloc(BK_MAX * 4);
    __half* W1img   = (__half*)alloc(128 * 128 * 2);
    __half* W2img   = (__half*)alloc(48 * 128 * 2);
    int*    ebuf    = (int*)   alloc((size_t)nbk * cap * 4);
    int*    col     = (int*)   alloc((size_t)nbk * cap * 4);
    __half* h1s     = (__half*)alloc((size_t)N * F_H * 2);
    __half* out1h   = (__half*)alloc((size_t)N * F_H * 2);
    __half* h2s     = h1s;     // h1s dead after agg1 -> reuse

    const int gC = (E + CHUNK - 1) / CHUNK;   // 391

    k_prep    <<<89, 256, 0, stream>>>(W1, W2, W1img, W2img, bcnt, nbk);
    k_bscatter<<<gC, 256, 0, stream>>>(src, dst, bcnt, ebuf, E, nbk, cap);
    k_bnode   <<<nbk, 256, 0, stream>>>(ebuf, bcnt, rbd, dinv, col, N, cap);

    k_gemm1<<<(N + 63) / 64, 256, 0, stream>>>(x, W1img, dinv, h1s, N);
    k_agg1r<<<(N + 3) / 4, 256, 0, stream>>>(h1s, rbd, col, dinv, b1, out1h, N);
    k_gemm2<<<(N + 63) / 64, 256, 0, stream>>>(out1h, W2img, dinv, h2s, N);
    k_agg2 <<<(N + 3) / 4, 256, 0, stream>>>(h2s, rbd, col, dinv, b2, out, N);
}